// Round 14
// baseline (136.392 us; speedup 1.0000x reference)
//
#include <hip/hip_runtime.h>
#include <math.h>

// B=64, A=64, MULS=((64,0),(32,1),(16,2)) -> DIM_IN=240, NB=32, H=128, MOUT=112
#define H_ 128
#define NB_ 32

#define INV_STEP 3.1f
#define HALF_PI 1.57079632679489662f
#define INV_SQRT_NB 0.17677669529663689f
#define INV_SQRT_H 0.08838834764831845f
#define NORM0 0.125f
#define NORM1 0.10206207261596575f
#define NORM2 0.11180339887498948f
#define S3 1.7320508075688772f
#define S5 2.23606797749979f
#define S15 3.872983346207417f
#define LN2 0.6931471805599453f

// base-2 ssp refactor: u = 5*log2e*x ; ssp(x) = (max(u,0)+log2(1+2^-|u|)-1)*K
#define SSP_K 0.13862943611198906f          // ln2/5
#define C_L1SC 1.2751763f                   // INV_SQRT_NB * 5*log2(e)
#define C_EPSC 0.63758714f                  // INV_SQRT_H  * 5*log2(e)

typedef __attribute__((ext_vector_type(8))) _Float16 half8;
typedef __attribute__((ext_vector_type(4))) float f32x4;

__device__ __forceinline__ float ssp_u(float u) {
    float e = __builtin_amdgcn_exp2f(-fabsf(u));
    float l = __builtin_amdgcn_logf(1.0f + e);
    float r = fmaxf(u, 0.0f) + l;
    return fmaf(r, SSP_K, -SSP_K);
}
__device__ __forceinline__ float sp_f(float x) {
    float t = 5.0f * x;
    float s = fmaxf(t, 0.0f) + __logf(1.0f + __expf(-fabsf(t)));
    return s * 0.2f;
}

// ---------------------------------------------------------------------------
// pair4: Round-14 = R13's 3-wave body FED BY A BIG ENOUGH GRID.
// R13 post-mortem: (256,3) + kt-unroll-2 worked (VGPR 68, no spill) but
// OccupancyPercent stayed 20% because grid was still 512 = 2 blocks/CU max
// (R4's lesson re-learned). Paid ILP (-15 µs exposure cost), got no waves.
// This round: bg split 8 -> 16 groups of 4 b's => grid 1024 => 3 blocks/CU
// resident at (256,3) => 12 waves/CU. Decomposition: issue ~25 µs (R12
// invariant) + exposure ~50*(2/3) ~ 33 => ~55 µs predicted.
// All numerics identical to R12/R13 (base-2 ssp, pkrtz, inline W2 staging).
// GATE: pair4 >= 60 µs => (ILP down, occ up) is net-zero; revert to R12.
// ---------------------------------------------------------------------------
__global__ __launch_bounds__(256, 3)
void pair4(const float* __restrict__ rep, const float* __restrict__ geom,
           const float* __restrict__ W1, const float* __restrict__ W2,
           const float* __restrict__ W3, _Float16* __restrict__ w2f,
           float* __restrict__ partial) {
    const int bg = blockIdx.x;           // b in [4bg, 4bg+4)
    const int z  = blockIdx.y;
    const int tid = threadIdx.x;
    const int wv = tid >> 6, lane = tid & 63;
    const int m = lane & 15, quad = lane >> 4;

    __shared__ __align__(16) _Float16 sVf[8192];       // 16384 B  [b<4][kt][lane][j]
    __shared__ __align__(16) _Float16 sH2t[4][16][40]; // 5120 B   per-wave [a][h2local+pad]
    __shared__ __align__(16) float sRep[960];          // 3840 B   4 rep rows
    __shared__ float sYw[4][2][16][8];                 // 4096 B
    __shared__ float sPosA[192];                       // 768 B
    __shared__ float sPosB[12];                        // 48 B
    // total ~30.2 KB -> LDS allows 5 blocks/CU; regs bind at 3

    // ---- W2 -> fp16 B-frags into global ws (every block, identical values) ----
    #pragma unroll 4
    for (int i = 0; i < 8; ++i) {
        const int pr = tid + i * 256;        // 0..2047
        const int ln = pr & 63, fn = pr >> 6;
        const int kt = fn >> 3, nt = fn & 7;
        const int krow = kt * 32 + (ln >> 4) * 8;
        const int n = nt * 16 + (ln & 15);
        const float* src = W2 + krow * 128 + n;
        half8 hv;
        #pragma unroll
        for (int j = 0; j < 8; ++j)
            hv[j] = (_Float16)src[j * 128];
        *reinterpret_cast<half8*>(w2f + (size_t)pr * 8) = hv;
    }

    // ---- startup: stage geom + rep ----
    if (tid < 192) sPosA[tid] = geom[z * 192 + tid];
    else if (tid < 204) sPosB[tid - 192] = geom[((size_t)z * 64 + bg * 4) * 3 + (tid - 192)];
    {
        const float4* src = reinterpret_cast<const float4*>(rep + ((size_t)z * 64 + bg * 4) * 240);
        float4* dst = reinterpret_cast<float4*>(sRep);
        if (tid < 240) dst[tid] = src[tid];
    }
    __syncthreads();

    // ---- V compute: 512 slots (b<4, h<128); emit fp16 B-frags ----
    #pragma unroll 2
    for (int i = 0; i < 2; ++i) {
        const int s = tid + i * 256;
        const int b = s >> 7, h = s & 127;
        const float* w3r = W3 + (size_t)h * 112;
        const float* rr = sRep + b * 240;
        float a0 = 0.f, a1 = 0.f, a2 = 0.f, a3 = 0.f, a4 = 0.f,
              a5 = 0.f, a6 = 0.f, a7 = 0.f, a8 = 0.f;
        #pragma unroll 4
        for (int m4 = 0; m4 < 16; ++m4) {            // l=0
            float4 w = *reinterpret_cast<const float4*>(w3r + m4 * 4);
            const float* wp = reinterpret_cast<const float*>(&w);
            #pragma unroll
            for (int c = 0; c < 4; ++c) a0 = fmaf(wp[c], rr[m4 * 4 + c], a0);
        }
        #pragma unroll 2
        for (int u4 = 0; u4 < 8; ++u4) {             // l=1
            float4 w = *reinterpret_cast<const float4*>(w3r + 64 + u4 * 4);
            const float* wp = reinterpret_cast<const float*>(&w);
            #pragma unroll
            for (int c = 0; c < 4; ++c) {
                int u = u4 * 4 + c;
                a1 = fmaf(wp[c], rr[64 + 3 * u + 0], a1);
                a2 = fmaf(wp[c], rr[64 + 3 * u + 1], a2);
                a3 = fmaf(wp[c], rr[64 + 3 * u + 2], a3);
            }
        }
        #pragma unroll 2
        for (int u4 = 0; u4 < 4; ++u4) {             // l=2
            float4 w = *reinterpret_cast<const float4*>(w3r + 96 + u4 * 4);
            const float* wp = reinterpret_cast<const float*>(&w);
            #pragma unroll
            for (int c = 0; c < 4; ++c) {
                int u = u4 * 4 + c;
                a4 = fmaf(wp[c], rr[160 + 5 * u + 0], a4);
                a5 = fmaf(wp[c], rr[160 + 5 * u + 1], a5);
                a6 = fmaf(wp[c], rr[160 + 5 * u + 2], a6);
                a7 = fmaf(wp[c], rr[160 + 5 * u + 3], a7);
                a8 = fmaf(wp[c], rr[160 + 5 * u + 4], a8);
            }
        }
        const float n0 = NORM0 * INV_SQRT_H, n1 = NORM1 * INV_SQRT_H, n2 = NORM2 * INV_SQRT_H;
        float vals[9];
        vals[0] = a0 * n0;
        vals[1] = a1 * n1; vals[2] = a2 * n1; vals[3] = a3 * n1;
        vals[4] = a4 * n2; vals[5] = a5 * n2; vals[6] = a6 * n2;
        vals[7] = a7 * n2; vals[8] = a8 * n2;
        // h = kt*32 + qd*8 + j ; frag pos = (b*4+kt)*512 + (qd*16+n)*8 + j
        const int kt = h >> 5, qd = (h >> 3) & 3, j = h & 7;
        _Float16* base = sVf + (b * 4 + kt) * 512 + qd * 128 + j;
        #pragma unroll
        for (int n = 0; n < 16; ++n)
            base[n * 8] = (n < 9) ? (_Float16)vals[n] : (_Float16)0.0f;
    }
    __syncthreads();   // sVf + sPos* ready; w2f writes drained (vmcnt0 @ barrier)

    // ---- main loop: 2 passes x 2-b pairs ----
    const int aLoc = wv * 16 + m;
    const float ax = sPosA[aLoc * 3 + 0];
    const float ay = sPosA[aLoc * 3 + 1];
    const float az = sPosA[aLoc * 3 + 2];
    float outAcc[4] = {0.f, 0.f, 0.f, 0.f};

    #pragma unroll 1
    for (int pass = 0; pass < 2; ++pass) {
        const float* w1p0[2];
        const float* w1p1[2];
        float c0v[2], c1v[2];

        #pragma unroll
        for (int p = 0; p < 2; ++p) {
            const int bl = pass * 2 + p;
            const float bx = sPosB[bl * 3 + 0];
            const float by = sPosB[bl * 3 + 1];
            const float bz = sPosB[bl * 3 + 2];
            const float dx = ax - bx, dy = ay - by, dz = az - bz;
            const float r2 = dx * dx + dy * dy + dz * dz;
            const float r = sqrtf(fmaxf(r2, 1e-12f));
            const float nzf = (r2 > 1e-10f) ? 1.0f : 0.0f;
            const float ir = 1.0f / r;
            const float x = dx * ir, y = dy * ir, zz = dz * ir;
            if (quad == 0) {
                float4 g0, g1;
                g0.x = S3 * x * nzf; g0.y = S3 * y * nzf; g0.z = S3 * zz * nzf;
                g0.w = S15 * x * y * nzf;
                g1.x = S15 * y * zz * nzf;
                g1.y = 0.5f * S5 * (3.0f * zz * zz - 1.0f) * nzf;
                g1.z = S15 * x * zz * nzf;
                g1.w = 0.5f * S15 * (x * x - y * y) * nzf;
                *reinterpret_cast<float4*>(&sYw[wv][p][m][0]) = g0;
                *reinterpret_cast<float4*>(&sYw[wv][p][m][4]) = g1;
            }
            const float u = r * INV_STEP;
            int i0 = (int)floorf(u);
            const float d0 = u - (float)i0;
            float c0 = (i0 >= 0 && i0 < NB_) ? __cosf(HALF_PI * d0) : 0.f;
            const int i1 = i0 + 1;
            const float d1 = d0 - 1.0f;
            float c1 = (i1 >= 0 && i1 < NB_ && d1 > -1.0f) ? __cosf(HALF_PI * d1) : 0.f;
            const int i0c = min(max(i0, 0), NB_ - 1);
            const int i1c = min(max(i1, 0), NB_ - 1);
            w1p0[p] = W1 + i0c * H_;
            w1p1[p] = W1 + i1c * H_;
            c0v[p] = c0 * C_L1SC;
            c1v[p] = c1 * C_L1SC;
        }

        f32x4 acc[2][8];
        #pragma unroll
        for (int p = 0; p < 2; ++p)
            #pragma unroll
            for (int nt = 0; nt < 8; ++nt) {
                acc[p][nt][0] = 0.f; acc[p][nt][1] = 0.f;
                acc[p][nt][2] = 0.f; acc[p][nt][3] = 0.f;
            }

        // ---- layer1 (base-2 ssp, pkrtz) + layer2 MFMA ----
        // unroll 2: 8 hoisted W1 float4s -> arch ~68 fits the 3-wave budget.
        #pragma unroll 2
        for (int kt = 0; kt < 4; ++kt) {
            const int koff = kt * 32 + quad * 8;
            half8 ah[2];
            #pragma unroll
            for (int p = 0; p < 2; ++p) {
                float4 wa0 = *reinterpret_cast<const float4*>(w1p0[p] + koff);
                float4 wa1 = *reinterpret_cast<const float4*>(w1p0[p] + koff + 4);
                float4 wb0 = *reinterpret_cast<const float4*>(w1p1[p] + koff);
                float4 wb1 = *reinterpret_cast<const float4*>(w1p1[p] + koff + 4);
                const float* a0p = reinterpret_cast<const float*>(&wa0);
                const float* a1p = reinterpret_cast<const float*>(&wa1);
                const float* b0p = reinterpret_cast<const float*>(&wb0);
                const float* b1p = reinterpret_cast<const float*>(&wb1);
                #pragma unroll
                for (int j2 = 0; j2 < 4; ++j2) {
                    const int j = j2 * 2;
                    float w0a = (j < 4) ? a0p[j] : a1p[j - 4];
                    float w1a = (j < 4) ? b0p[j] : b1p[j - 4];
                    float w0b = (j + 1 < 4) ? a0p[j + 1] : a1p[j - 3];
                    float w1b = (j + 1 < 4) ? b0p[j + 1] : b1p[j - 3];
                    float ua = fmaf(c0v[p], w0a, c1v[p] * w1a);
                    float ub = fmaf(c0v[p], w0b, c1v[p] * w1b);
                    auto pk = __builtin_amdgcn_cvt_pkrtz(ssp_u(ua), ssp_u(ub));
                    ah[p][j] = pk[0];
                    ah[p][j + 1] = pk[1];
                }
            }
            const _Float16* bhp = w2f + (size_t)(kt * 8) * 512 + (size_t)lane * 8;
            #pragma unroll
            for (int nt = 0; nt < 8; ++nt) {
                half8 bh = *reinterpret_cast<const half8*>(bhp + nt * 512);
                acc[0][nt] = __builtin_amdgcn_mfma_f32_16x16x32_f16(ah[0], bh, acc[0][nt], 0, 0, 0);
                acc[1][nt] = __builtin_amdgcn_mfma_f32_16x16x32_f16(ah[1], bh, acc[1][nt], 0, 0, 0);
            }
        }

        // ---- per-b epilogue ----
        #pragma unroll
        for (int p = 0; p < 2; ++p) {
            const int bl = pass * 2 + p;

            f32x4 T0 = {0.f, 0.f, 0.f, 0.f};
            f32x4 T1 = {0.f, 0.f, 0.f, 0.f};
            #pragma unroll
            for (int kt = 0; kt < 4; ++kt) {
                #pragma unroll
                for (int ntl = 0; ntl < 2; ++ntl)
                    #pragma unroll
                    for (int reg = 0; reg < 4; ++reg)
                        sH2t[wv][quad * 4 + reg][ntl * 16 + m] =
                            (_Float16)ssp_u(acc[p][kt * 2 + ntl][reg] * C_EPSC);
                half8 ah2 = *reinterpret_cast<const half8*>(&sH2t[wv][m][quad * 8]);
                half8 bv = *reinterpret_cast<const half8*>(sVf + (bl * 4 + kt) * 512 + lane * 8);
                if (kt & 1) T1 = __builtin_amdgcn_mfma_f32_16x16x32_f16(ah2, bv, T1, 0, 0, 0);
                else        T0 = __builtin_amdgcn_mfma_f32_16x16x32_f16(ah2, bv, T0, 0, 0, 0);
            }

            // G-weight; reduce DEFERRED
            const int comp = (m >= 1 && m <= 8) ? (m - 1) : 0;
            #pragma unroll
            for (int reg = 0; reg < 4; ++reg) {
                const int row = quad * 4 + reg;
                const float Tv = T0[reg] + T1[reg];
                const float yv = sYw[wv][p][row][comp];
                const float g = (m == 0) ? 1.0f : ((m <= 8) ? yv : 0.0f);
                outAcc[reg] = fmaf(Tv, g, outAcc[reg]);
            }
        }
    }

    // ---- single 16-lane shuffle reduce ----
    #pragma unroll
    for (int off = 1; off < 16; off <<= 1)
        #pragma unroll
        for (int reg = 0; reg < 4; ++reg)
            outAcc[reg] += __shfl_xor(outAcc[reg], off);

    // ---- write partial[z][bg][a]: lanes m==0 hold a = wv*16 + quad*4 + reg ----
    if (m == 0) {
        float4 st;
        st.x = outAcc[0]; st.y = outAcc[1]; st.z = outAcc[2]; st.w = outAcc[3];
        *reinterpret_cast<float4*>(partial + ((size_t)(z * 16 + bg)) * 64 + wv * 16 + quad * 4) = st;
    }
}

// ---------------------------------------------------------------------------
// finalize: out[z,a] = sp( (sum_bg partial) / sqrt(n_atoms) ) * mask
// ---------------------------------------------------------------------------
__global__ __launch_bounds__(64, 8)
void finalize(const float* __restrict__ partial, const float* __restrict__ mask,
              float* __restrict__ out) {
    const int z = blockIdx.x, a = threadIdx.x;
    const float mk = mask[z * 64 + a];
    float s = mk;
    #pragma unroll
    for (int off = 32; off > 0; off >>= 1) s += __shfl_xor(s, off);
    const float inv = rsqrtf(s);
    float acc = 0.f;
    #pragma unroll
    for (int bg = 0; bg < 16; ++bg)
        acc += partial[((size_t)(z * 16 + bg)) * 64 + a];
    out[z * 64 + a] = sp_f(acc * inv) * mk;
}

extern "C" void kernel_launch(void* const* d_in, const int* in_sizes, int n_in,
                              void* d_out, int out_size, void* d_ws, size_t ws_size,
                              hipStream_t stream) {
    const float* rep  = (const float*)d_in[0];
    const float* geom = (const float*)d_in[1];
    const float* mask = (const float*)d_in[2];
    const float* W1   = (const float*)d_in[3];
    const float* W2   = (const float*)d_in[4];
    const float* W3   = (const float*)d_in[5];
    float* out = (float*)d_out;

    _Float16* w2f = (_Float16*)d_ws;                          // 32768 B
    float* partial = (float*)((char*)d_ws + 32768);           // 64*16*64*4 = 262144 B

    pair4<<<dim3(16, 64), 256, 0, stream>>>(rep, geom, W1, W2, W3, w2f, partial);
    finalize<<<64, 64, 0, stream>>>(partial, mask, out);
}

// Round 15
// 123.830 us; speedup vs baseline: 1.1014x; 1.1014x over previous
//
#include <hip/hip_runtime.h>
#include <math.h>

// B=64, A=64, MULS=((64,0),(32,1),(16,2)) -> DIM_IN=240, NB=32, H=128, MOUT=112
#define H_ 128
#define NB_ 32

#define INV_STEP 3.1f
#define HALF_PI 1.57079632679489662f
#define INV_SQRT_NB 0.17677669529663689f
#define INV_SQRT_H 0.08838834764831845f
#define NORM0 0.125f
#define NORM1 0.10206207261596575f
#define NORM2 0.11180339887498948f
#define S3 1.7320508075688772f
#define S5 2.23606797749979f
#define S15 3.872983346207417f
#define LN2 0.6931471805599453f

// base-2 ssp refactor: u = 5*log2e*x ; ssp(x) = (max(u,0)+log2(1+2^-|u|)-1)*K
#define SSP_K 0.13862943611198906f          // ln2/5
#define C_L1SC 1.2751763f                   // INV_SQRT_NB * 5*log2(e)
#define C_EPSC 0.63758714f                  // INV_SQRT_H  * 5*log2(e)

typedef __attribute__((ext_vector_type(8))) _Float16 half8;
typedef __attribute__((ext_vector_type(4))) float f32x4;

__device__ __forceinline__ float ssp_u(float u) {
    float e = __builtin_amdgcn_exp2f(-fabsf(u));
    float l = __builtin_amdgcn_logf(1.0f + e);
    float r = fmaxf(u, 0.0f) + l;
    return fmaf(r, SSP_K, -SSP_K);
}
__device__ __forceinline__ float sp_f(float x) {
    float t = 5.0f * x;
    float s = fmaxf(t, 0.0f) + __logf(1.0f + __expf(-fabsf(t)));
    return s * 0.2f;
}

// ---------------------------------------------------------------------------
// pair4: Round-15 = R12 VERBATIM (measured 60 µs pair4 / 116.2 total — the
// session best; R13/R14 proved the occupancy lever non-actionable: 3rd block
// never became resident, ILP cuts cost 15-20 µs) + ONE epilogue latency cut:
//   The per-kt transpose did {8 LDS writes -> lgkmcnt drain -> read} x4 per
//   b (compiler must drain the wave's own ds_writes before each ds_read).
//   Widening sH2t to full H2 width [16][136] fp16 (+12 KB LDS, still 2
//   blocks/CU: 62.8x2=126<160 KB) lets all 32 writes issue before ONE drain
//   serving all 4 kt reads: 3 of 4 round-trip stalls per b deleted.
//   Row stride 136 fp16 = 272 B keeps b128 reads 16B-aligned and at the
//   LDS data-volume floor (start banks uniform over the 8 4-bank groups).
// Everything else byte-identical to R12.
// ---------------------------------------------------------------------------
__global__ __launch_bounds__(256, 2)
void pair4(const float* __restrict__ rep, const float* __restrict__ geom,
           const float* __restrict__ W1, const float* __restrict__ W2,
           const float* __restrict__ W3, _Float16* __restrict__ w2f,
           float* __restrict__ partial) {
    const int bg = blockIdx.x;           // b in [8bg, 8bg+8)
    const int z  = blockIdx.y;
    const int tid = threadIdx.x;
    const int wv = tid >> 6, lane = tid & 63;
    const int m = lane & 15, quad = lane >> 4;

    __shared__ __align__(16) _Float16 sVf[16384];       // 32768 B  [b<8][kt][lane][j]
    __shared__ __align__(16) _Float16 sH2t[4][16][136]; // 17408 B  per-wave [a][h2 full+pad]
    __shared__ __align__(16) float sRep[1920];          // 7680 B   8 rep rows
    __shared__ float sYw[4][2][16][8];                  // 4096 B
    __shared__ float sPosA[192];                        // 768 B
    __shared__ float sPosB[24];                         // 96 B
    // total ~62.8 KB; 2 blocks/CU (125.6 KB < 160 KB); reg-bound anyway

    // ---- W2 -> fp16 B-frags into global ws (every block, identical values) ----
    #pragma unroll
    for (int i = 0; i < 8; ++i) {
        const int pr = tid + i * 256;        // 0..2047
        const int ln = pr & 63, fn = pr >> 6;
        const int kt = fn >> 3, nt = fn & 7;
        const int krow = kt * 32 + (ln >> 4) * 8;
        const int n = nt * 16 + (ln & 15);
        const float* src = W2 + krow * 128 + n;
        half8 hv;
        #pragma unroll
        for (int j = 0; j < 8; ++j)
            hv[j] = (_Float16)src[j * 128];
        *reinterpret_cast<half8*>(w2f + (size_t)pr * 8) = hv;
    }

    // ---- startup: stage geom + rep ----
    if (tid < 192) sPosA[tid] = geom[z * 192 + tid];
    else if (tid < 216) sPosB[tid - 192] = geom[((size_t)z * 64 + bg * 8) * 3 + (tid - 192)];
    {
        const float4* src = reinterpret_cast<const float4*>(rep + ((size_t)z * 64 + bg * 8) * 240);
        float4* dst = reinterpret_cast<float4*>(sRep);
        for (int i = tid; i < 480; i += 256) dst[i] = src[i];
    }
    __syncthreads();

    // ---- V compute: 1024 slots (b,h); emit fp16 B-frags (16 n's incl. zeros) ----
    #pragma unroll
    for (int i = 0; i < 4; ++i) {
        const int s = tid + i * 256;
        const int b = s >> 7, h = s & 127;
        const float* w3r = W3 + (size_t)h * 112;
        const float* rr = sRep + b * 240;
        float a0 = 0.f, a1 = 0.f, a2 = 0.f, a3 = 0.f, a4 = 0.f,
              a5 = 0.f, a6 = 0.f, a7 = 0.f, a8 = 0.f;
        #pragma unroll 4
        for (int m4 = 0; m4 < 16; ++m4) {            // l=0
            float4 w = *reinterpret_cast<const float4*>(w3r + m4 * 4);
            const float* wp = reinterpret_cast<const float*>(&w);
            #pragma unroll
            for (int c = 0; c < 4; ++c) a0 = fmaf(wp[c], rr[m4 * 4 + c], a0);
        }
        #pragma unroll 2
        for (int u4 = 0; u4 < 8; ++u4) {             // l=1
            float4 w = *reinterpret_cast<const float4*>(w3r + 64 + u4 * 4);
            const float* wp = reinterpret_cast<const float*>(&w);
            #pragma unroll
            for (int c = 0; c < 4; ++c) {
                int u = u4 * 4 + c;
                a1 = fmaf(wp[c], rr[64 + 3 * u + 0], a1);
                a2 = fmaf(wp[c], rr[64 + 3 * u + 1], a2);
                a3 = fmaf(wp[c], rr[64 + 3 * u + 2], a3);
            }
        }
        #pragma unroll 2
        for (int u4 = 0; u4 < 4; ++u4) {             // l=2
            float4 w = *reinterpret_cast<const float4*>(w3r + 96 + u4 * 4);
            const float* wp = reinterpret_cast<const float*>(&w);
            #pragma unroll
            for (int c = 0; c < 4; ++c) {
                int u = u4 * 4 + c;
                a4 = fmaf(wp[c], rr[160 + 5 * u + 0], a4);
                a5 = fmaf(wp[c], rr[160 + 5 * u + 1], a5);
                a6 = fmaf(wp[c], rr[160 + 5 * u + 2], a6);
                a7 = fmaf(wp[c], rr[160 + 5 * u + 3], a7);
                a8 = fmaf(wp[c], rr[160 + 5 * u + 4], a8);
            }
        }
        const float n0 = NORM0 * INV_SQRT_H, n1 = NORM1 * INV_SQRT_H, n2 = NORM2 * INV_SQRT_H;
        float vals[9];
        vals[0] = a0 * n0;
        vals[1] = a1 * n1; vals[2] = a2 * n1; vals[3] = a3 * n1;
        vals[4] = a4 * n2; vals[5] = a5 * n2; vals[6] = a6 * n2;
        vals[7] = a7 * n2; vals[8] = a8 * n2;
        // h = kt*32 + qd*8 + j ; frag pos = (b*4+kt)*512 + (qd*16+n)*8 + j
        const int kt = h >> 5, qd = (h >> 3) & 3, j = h & 7;
        _Float16* base = sVf + (b * 4 + kt) * 512 + qd * 128 + j;
        #pragma unroll
        for (int n = 0; n < 16; ++n)
            base[n * 8] = (n < 9) ? (_Float16)vals[n] : (_Float16)0.0f;
    }
    __syncthreads();   // sVf + sPos* ready; w2f writes drained (vmcnt0 @ barrier)

    // ---- main loop: 4 passes x 2-b pairs (R8/R12's proven structure) ----
    const int aLoc = wv * 16 + m;
    const float ax = sPosA[aLoc * 3 + 0];
    const float ay = sPosA[aLoc * 3 + 1];
    const float az = sPosA[aLoc * 3 + 2];
    float outAcc[4] = {0.f, 0.f, 0.f, 0.f};

    for (int pass = 0; pass < 4; ++pass) {
        const float* w1p0[2];
        const float* w1p1[2];
        float c0v[2], c1v[2];

        #pragma unroll
        for (int p = 0; p < 2; ++p) {
            const int bl = pass * 2 + p;
            const float bx = sPosB[bl * 3 + 0];
            const float by = sPosB[bl * 3 + 1];
            const float bz = sPosB[bl * 3 + 2];
            const float dx = ax - bx, dy = ay - by, dz = az - bz;
            const float r2 = dx * dx + dy * dy + dz * dz;
            const float r = sqrtf(fmaxf(r2, 1e-12f));
            const float nzf = (r2 > 1e-10f) ? 1.0f : 0.0f;
            const float ir = 1.0f / r;
            const float x = dx * ir, y = dy * ir, zz = dz * ir;
            if (quad == 0) {
                float4 g0, g1;
                g0.x = S3 * x * nzf; g0.y = S3 * y * nzf; g0.z = S3 * zz * nzf;
                g0.w = S15 * x * y * nzf;
                g1.x = S15 * y * zz * nzf;
                g1.y = 0.5f * S5 * (3.0f * zz * zz - 1.0f) * nzf;
                g1.z = S15 * x * zz * nzf;
                g1.w = 0.5f * S15 * (x * x - y * y) * nzf;
                *reinterpret_cast<float4*>(&sYw[wv][p][m][0]) = g0;
                *reinterpret_cast<float4*>(&sYw[wv][p][m][4]) = g1;
            }
            const float u = r * INV_STEP;
            int i0 = (int)floorf(u);
            const float d0 = u - (float)i0;
            float c0 = (i0 >= 0 && i0 < NB_) ? __cosf(HALF_PI * d0) : 0.f;
            const int i1 = i0 + 1;
            const float d1 = d0 - 1.0f;
            float c1 = (i1 >= 0 && i1 < NB_ && d1 > -1.0f) ? __cosf(HALF_PI * d1) : 0.f;
            const int i0c = min(max(i0, 0), NB_ - 1);
            const int i1c = min(max(i1, 0), NB_ - 1);
            w1p0[p] = W1 + i0c * H_;
            w1p1[p] = W1 + i1c * H_;
            c0v[p] = c0 * C_L1SC;
            c1v[p] = c1 * C_L1SC;
        }

        f32x4 acc[2][8];
        #pragma unroll
        for (int p = 0; p < 2; ++p)
            #pragma unroll
            for (int nt = 0; nt < 8; ++nt) {
                acc[p][nt][0] = 0.f; acc[p][nt][1] = 0.f;
                acc[p][nt][2] = 0.f; acc[p][nt][3] = 0.f;
            }

        // ---- layer1 (base-2 ssp, pkrtz) + layer2 MFMA (full kt unroll) ----
        #pragma unroll
        for (int kt = 0; kt < 4; ++kt) {
            const int koff = kt * 32 + quad * 8;
            half8 ah[2];
            #pragma unroll
            for (int p = 0; p < 2; ++p) {
                float4 wa0 = *reinterpret_cast<const float4*>(w1p0[p] + koff);
                float4 wa1 = *reinterpret_cast<const float4*>(w1p0[p] + koff + 4);
                float4 wb0 = *reinterpret_cast<const float4*>(w1p1[p] + koff);
                float4 wb1 = *reinterpret_cast<const float4*>(w1p1[p] + koff + 4);
                const float* a0p = reinterpret_cast<const float*>(&wa0);
                const float* a1p = reinterpret_cast<const float*>(&wa1);
                const float* b0p = reinterpret_cast<const float*>(&wb0);
                const float* b1p = reinterpret_cast<const float*>(&wb1);
                #pragma unroll
                for (int j2 = 0; j2 < 4; ++j2) {
                    const int j = j2 * 2;
                    float w0a = (j < 4) ? a0p[j] : a1p[j - 4];
                    float w1a = (j < 4) ? b0p[j] : b1p[j - 4];
                    float w0b = (j + 1 < 4) ? a0p[j + 1] : a1p[j - 3];
                    float w1b = (j + 1 < 4) ? b0p[j + 1] : b1p[j - 3];
                    float ua = fmaf(c0v[p], w0a, c1v[p] * w1a);
                    float ub = fmaf(c0v[p], w0b, c1v[p] * w1b);
                    auto pk = __builtin_amdgcn_cvt_pkrtz(ssp_u(ua), ssp_u(ub));
                    ah[p][j] = pk[0];
                    ah[p][j + 1] = pk[1];
                }
            }
            const _Float16* bhp = w2f + (size_t)(kt * 8) * 512 + (size_t)lane * 8;
            #pragma unroll
            for (int nt = 0; nt < 8; ++nt) {
                half8 bh = *reinterpret_cast<const half8*>(bhp + nt * 512);
                acc[0][nt] = __builtin_amdgcn_mfma_f32_16x16x32_f16(ah[0], bh, acc[0][nt], 0, 0, 0);
                acc[1][nt] = __builtin_amdgcn_mfma_f32_16x16x32_f16(ah[1], bh, acc[1][nt], 0, 0, 0);
            }
        }

        // ---- per-b epilogue: ALL 32 transpose writes, ONE drain, 4 kt reads ----
        #pragma unroll
        for (int p = 0; p < 2; ++p) {
            const int bl = pass * 2 + p;

            #pragma unroll
            for (int nt = 0; nt < 8; ++nt)
                #pragma unroll
                for (int reg = 0; reg < 4; ++reg)
                    sH2t[wv][quad * 4 + reg][nt * 16 + m] =
                        (_Float16)ssp_u(acc[p][nt][reg] * C_EPSC);

            f32x4 T0 = {0.f, 0.f, 0.f, 0.f};
            f32x4 T1 = {0.f, 0.f, 0.f, 0.f};
            #pragma unroll
            for (int kt = 0; kt < 4; ++kt) {
                half8 ah2 = *reinterpret_cast<const half8*>(&sH2t[wv][m][kt * 32 + quad * 8]);
                half8 bv = *reinterpret_cast<const half8*>(sVf + (bl * 4 + kt) * 512 + lane * 8);
                if (kt & 1) T1 = __builtin_amdgcn_mfma_f32_16x16x32_f16(ah2, bv, T1, 0, 0, 0);
                else        T0 = __builtin_amdgcn_mfma_f32_16x16x32_f16(ah2, bv, T0, 0, 0, 0);
            }

            // G-weight; reduce DEFERRED
            const int comp = (m >= 1 && m <= 8) ? (m - 1) : 0;
            #pragma unroll
            for (int reg = 0; reg < 4; ++reg) {
                const int row = quad * 4 + reg;
                const float Tv = T0[reg] + T1[reg];
                const float yv = sYw[wv][p][row][comp];
                const float g = (m == 0) ? 1.0f : ((m <= 8) ? yv : 0.0f);
                outAcc[reg] = fmaf(Tv, g, outAcc[reg]);
            }
        }
    }

    // ---- single 16-lane shuffle reduce ----
    #pragma unroll
    for (int off = 1; off < 16; off <<= 1)
        #pragma unroll
        for (int reg = 0; reg < 4; ++reg)
            outAcc[reg] += __shfl_xor(outAcc[reg], off);

    // ---- write partial[z][bg][a]: lanes m==0 hold a = wv*16 + quad*4 + reg ----
    if (m == 0) {
        float4 st;
        st.x = outAcc[0]; st.y = outAcc[1]; st.z = outAcc[2]; st.w = outAcc[3];
        *reinterpret_cast<float4*>(partial + ((size_t)(z * 8 + bg)) * 64 + wv * 16 + quad * 4) = st;
    }
}

// ---------------------------------------------------------------------------
// finalize: out[z,a] = sp( (sum_bg partial) / sqrt(n_atoms) ) * mask
// ---------------------------------------------------------------------------
__global__ __launch_bounds__(64, 8)
void finalize(const float* __restrict__ partial, const float* __restrict__ mask,
              float* __restrict__ out) {
    const int z = blockIdx.x, a = threadIdx.x;
    const float mk = mask[z * 64 + a];
    float s = mk;
    #pragma unroll
    for (int off = 32; off > 0; off >>= 1) s += __shfl_xor(s, off);
    const float inv = rsqrtf(s);
    float acc = 0.f;
    #pragma unroll
    for (int bg = 0; bg < 8; ++bg)
        acc += partial[((size_t)(z * 8 + bg)) * 64 + a];
    out[z * 64 + a] = sp_f(acc * inv) * mk;
}

extern "C" void kernel_launch(void* const* d_in, const int* in_sizes, int n_in,
                              void* d_out, int out_size, void* d_ws, size_t ws_size,
                              hipStream_t stream) {
    const float* rep  = (const float*)d_in[0];
    const float* geom = (const float*)d_in[1];
    const float* mask = (const float*)d_in[2];
    const float* W1   = (const float*)d_in[3];
    const float* W2   = (const float*)d_in[4];
    const float* W3   = (const float*)d_in[5];
    float* out = (float*)d_out;

    _Float16* w2f = (_Float16*)d_ws;                          // 32768 B
    float* partial = (float*)((char*)d_ws + 32768);           // 512*64*4 = 131072 B

    pair4<<<dim3(8, 64), 256, 0, stream>>>(rep, geom, W1, W2, W3, w2f, partial);
    finalize<<<64, 64, 0, stream>>>(partial, mask, out);
}

// Round 16
// 115.672 us; speedup vs baseline: 1.1791x; 1.0705x over previous
//
#include <hip/hip_runtime.h>
#include <math.h>

// B=64, A=64, MULS=((64,0),(32,1),(16,2)) -> DIM_IN=240, NB=32, H=128, MOUT=112
#define H_ 128
#define NB_ 32

#define INV_STEP 3.1f
#define HALF_PI 1.57079632679489662f
#define INV_SQRT_NB 0.17677669529663689f
#define INV_SQRT_H 0.08838834764831845f
#define NORM0 0.125f
#define NORM1 0.10206207261596575f
#define NORM2 0.11180339887498948f
#define S3 1.7320508075688772f
#define S5 2.23606797749979f
#define S15 3.872983346207417f
#define LN2 0.6931471805599453f

// base-2 ssp refactor: u = 5*log2e*x ; ssp(x) = (max(u,0)+log2(1+2^-|u|)-1)*K
#define SSP_K 0.13862943611198906f          // ln2/5
#define C_L1SC 1.2751763f                   // INV_SQRT_NB * 5*log2(e)
#define C_EPSC 0.63758714f                  // INV_SQRT_H  * 5*log2(e)

typedef __attribute__((ext_vector_type(8))) _Float16 half8;
typedef __attribute__((ext_vector_type(4))) float f32x4;

__device__ __forceinline__ float ssp_u(float u) {
    float e = __builtin_amdgcn_exp2f(-fabsf(u));
    float l = __builtin_amdgcn_logf(1.0f + e);
    float r = fmaxf(u, 0.0f) + l;
    return fmaf(r, SSP_K, -SSP_K);
}
__device__ __forceinline__ float sp_f(float x) {
    float t = 5.0f * x;
    float s = fmaxf(t, 0.0f) + __logf(1.0f + __expf(-fabsf(t)));
    return s * 0.2f;
}

// ---------------------------------------------------------------------------
// pair4: Round-16 = R12 VERBATIM (the measured session best: pair4 60.1 µs,
// total 116.2 µs). R15's wide-sH2t epilogue experiment tripped its gate:
// VGPR hit the 128 cap and spilled (WRITE_SIZE 0.4 -> 10.6 MB), pair4 68 µs.
// Session ledger at close:
//   issue floor  ~25 µs  (base-2 ssp + pkrtz cut it from 47-50)
//   exposure     ~35 µs  (occupancy non-actionable R13/R14; ILP maxed R15;
//                         LDS-pipe moves regress R9; fences regress R6/R7)
//   harness floor ~55 µs (fixed across 2- and 3-launch configs R9/R10/R11)
// ---------------------------------------------------------------------------
__global__ __launch_bounds__(256, 2)
void pair4(const float* __restrict__ rep, const float* __restrict__ geom,
           const float* __restrict__ W1, const float* __restrict__ W2,
           const float* __restrict__ W3, _Float16* __restrict__ w2f,
           float* __restrict__ partial) {
    const int bg = blockIdx.x;           // b in [8bg, 8bg+8)
    const int z  = blockIdx.y;
    const int tid = threadIdx.x;
    const int wv = tid >> 6, lane = tid & 63;
    const int m = lane & 15, quad = lane >> 4;

    __shared__ __align__(16) _Float16 sVf[16384];      // 32768 B  [b<8][kt][lane][j]
    __shared__ __align__(16) _Float16 sH2t[4][16][40]; // 5120 B   per-wave [a][h2local+pad]
    __shared__ __align__(16) float sRep[1920];         // 7680 B   8 rep rows
    __shared__ float sYw[4][2][16][8];                 // 4096 B
    __shared__ float sPosA[192];                       // 768 B
    __shared__ float sPosB[24];                        // 96 B
    // total ~50.6 KB; reg-bound 2 blocks/CU

    // ---- W2 -> fp16 B-frags into global ws (every block, identical values) ----
    #pragma unroll
    for (int i = 0; i < 8; ++i) {
        const int pr = tid + i * 256;        // 0..2047
        const int ln = pr & 63, fn = pr >> 6;
        const int kt = fn >> 3, nt = fn & 7;
        const int krow = kt * 32 + (ln >> 4) * 8;
        const int n = nt * 16 + (ln & 15);
        const float* src = W2 + krow * 128 + n;
        half8 hv;
        #pragma unroll
        for (int j = 0; j < 8; ++j)
            hv[j] = (_Float16)src[j * 128];
        *reinterpret_cast<half8*>(w2f + (size_t)pr * 8) = hv;
    }

    // ---- startup: stage geom + rep ----
    if (tid < 192) sPosA[tid] = geom[z * 192 + tid];
    else if (tid < 216) sPosB[tid - 192] = geom[((size_t)z * 64 + bg * 8) * 3 + (tid - 192)];
    {
        const float4* src = reinterpret_cast<const float4*>(rep + ((size_t)z * 64 + bg * 8) * 240);
        float4* dst = reinterpret_cast<float4*>(sRep);
        for (int i = tid; i < 480; i += 256) dst[i] = src[i];
    }
    __syncthreads();

    // ---- V compute: 1024 slots (b,h); emit fp16 B-frags (16 n's incl. zeros) ----
    #pragma unroll
    for (int i = 0; i < 4; ++i) {
        const int s = tid + i * 256;
        const int b = s >> 7, h = s & 127;
        const float* w3r = W3 + (size_t)h * 112;
        const float* rr = sRep + b * 240;
        float a0 = 0.f, a1 = 0.f, a2 = 0.f, a3 = 0.f, a4 = 0.f,
              a5 = 0.f, a6 = 0.f, a7 = 0.f, a8 = 0.f;
        #pragma unroll 4
        for (int m4 = 0; m4 < 16; ++m4) {            // l=0
            float4 w = *reinterpret_cast<const float4*>(w3r + m4 * 4);
            const float* wp = reinterpret_cast<const float*>(&w);
            #pragma unroll
            for (int c = 0; c < 4; ++c) a0 = fmaf(wp[c], rr[m4 * 4 + c], a0);
        }
        #pragma unroll 2
        for (int u4 = 0; u4 < 8; ++u4) {             // l=1
            float4 w = *reinterpret_cast<const float4*>(w3r + 64 + u4 * 4);
            const float* wp = reinterpret_cast<const float*>(&w);
            #pragma unroll
            for (int c = 0; c < 4; ++c) {
                int u = u4 * 4 + c;
                a1 = fmaf(wp[c], rr[64 + 3 * u + 0], a1);
                a2 = fmaf(wp[c], rr[64 + 3 * u + 1], a2);
                a3 = fmaf(wp[c], rr[64 + 3 * u + 2], a3);
            }
        }
        #pragma unroll 2
        for (int u4 = 0; u4 < 4; ++u4) {             // l=2
            float4 w = *reinterpret_cast<const float4*>(w3r + 96 + u4 * 4);
            const float* wp = reinterpret_cast<const float*>(&w);
            #pragma unroll
            for (int c = 0; c < 4; ++c) {
                int u = u4 * 4 + c;
                a4 = fmaf(wp[c], rr[160 + 5 * u + 0], a4);
                a5 = fmaf(wp[c], rr[160 + 5 * u + 1], a5);
                a6 = fmaf(wp[c], rr[160 + 5 * u + 2], a6);
                a7 = fmaf(wp[c], rr[160 + 5 * u + 3], a7);
                a8 = fmaf(wp[c], rr[160 + 5 * u + 4], a8);
            }
        }
        const float n0 = NORM0 * INV_SQRT_H, n1 = NORM1 * INV_SQRT_H, n2 = NORM2 * INV_SQRT_H;
        float vals[9];
        vals[0] = a0 * n0;
        vals[1] = a1 * n1; vals[2] = a2 * n1; vals[3] = a3 * n1;
        vals[4] = a4 * n2; vals[5] = a5 * n2; vals[6] = a6 * n2;
        vals[7] = a7 * n2; vals[8] = a8 * n2;
        // h = kt*32 + qd*8 + j ; frag pos = (b*4+kt)*512 + (qd*16+n)*8 + j
        const int kt = h >> 5, qd = (h >> 3) & 3, j = h & 7;
        _Float16* base = sVf + (b * 4 + kt) * 512 + qd * 128 + j;
        #pragma unroll
        for (int n = 0; n < 16; ++n)
            base[n * 8] = (n < 9) ? (_Float16)vals[n] : (_Float16)0.0f;
    }
    __syncthreads();   // sVf + sPos* ready; w2f writes drained (vmcnt0 @ barrier)

    // ---- main loop: 4 passes x 2-b pairs (R8's proven structure) ----
    const int aLoc = wv * 16 + m;
    const float ax = sPosA[aLoc * 3 + 0];
    const float ay = sPosA[aLoc * 3 + 1];
    const float az = sPosA[aLoc * 3 + 2];
    float outAcc[4] = {0.f, 0.f, 0.f, 0.f};

    for (int pass = 0; pass < 4; ++pass) {
        const float* w1p0[2];
        const float* w1p1[2];
        float c0v[2], c1v[2];

        #pragma unroll
        for (int p = 0; p < 2; ++p) {
            const int bl = pass * 2 + p;
            const float bx = sPosB[bl * 3 + 0];
            const float by = sPosB[bl * 3 + 1];
            const float bz = sPosB[bl * 3 + 2];
            const float dx = ax - bx, dy = ay - by, dz = az - bz;
            const float r2 = dx * dx + dy * dy + dz * dz;
            const float r = sqrtf(fmaxf(r2, 1e-12f));
            const float nzf = (r2 > 1e-10f) ? 1.0f : 0.0f;
            const float ir = 1.0f / r;
            const float x = dx * ir, y = dy * ir, zz = dz * ir;
            if (quad == 0) {
                float4 g0, g1;
                g0.x = S3 * x * nzf; g0.y = S3 * y * nzf; g0.z = S3 * zz * nzf;
                g0.w = S15 * x * y * nzf;
                g1.x = S15 * y * zz * nzf;
                g1.y = 0.5f * S5 * (3.0f * zz * zz - 1.0f) * nzf;
                g1.z = S15 * x * zz * nzf;
                g1.w = 0.5f * S15 * (x * x - y * y) * nzf;
                *reinterpret_cast<float4*>(&sYw[wv][p][m][0]) = g0;
                *reinterpret_cast<float4*>(&sYw[wv][p][m][4]) = g1;
            }
            const float u = r * INV_STEP;
            int i0 = (int)floorf(u);
            const float d0 = u - (float)i0;
            float c0 = (i0 >= 0 && i0 < NB_) ? __cosf(HALF_PI * d0) : 0.f;
            const int i1 = i0 + 1;
            const float d1 = d0 - 1.0f;
            float c1 = (i1 >= 0 && i1 < NB_ && d1 > -1.0f) ? __cosf(HALF_PI * d1) : 0.f;
            const int i0c = min(max(i0, 0), NB_ - 1);
            const int i1c = min(max(i1, 0), NB_ - 1);
            w1p0[p] = W1 + i0c * H_;
            w1p1[p] = W1 + i1c * H_;
            c0v[p] = c0 * C_L1SC;
            c1v[p] = c1 * C_L1SC;
        }

        f32x4 acc[2][8];
        #pragma unroll
        for (int p = 0; p < 2; ++p)
            #pragma unroll
            for (int nt = 0; nt < 8; ++nt) {
                acc[p][nt][0] = 0.f; acc[p][nt][1] = 0.f;
                acc[p][nt][2] = 0.f; acc[p][nt][3] = 0.f;
            }

        // ---- layer1 (base-2 ssp, pkrtz) + layer2 MFMA ----
        #pragma unroll
        for (int kt = 0; kt < 4; ++kt) {
            const int koff = kt * 32 + quad * 8;
            half8 ah[2];
            #pragma unroll
            for (int p = 0; p < 2; ++p) {
                float4 wa0 = *reinterpret_cast<const float4*>(w1p0[p] + koff);
                float4 wa1 = *reinterpret_cast<const float4*>(w1p0[p] + koff + 4);
                float4 wb0 = *reinterpret_cast<const float4*>(w1p1[p] + koff);
                float4 wb1 = *reinterpret_cast<const float4*>(w1p1[p] + koff + 4);
                const float* a0p = reinterpret_cast<const float*>(&wa0);
                const float* a1p = reinterpret_cast<const float*>(&wa1);
                const float* b0p = reinterpret_cast<const float*>(&wb0);
                const float* b1p = reinterpret_cast<const float*>(&wb1);
                #pragma unroll
                for (int j2 = 0; j2 < 4; ++j2) {
                    const int j = j2 * 2;
                    float w0a = (j < 4) ? a0p[j] : a1p[j - 4];
                    float w1a = (j < 4) ? b0p[j] : b1p[j - 4];
                    float w0b = (j + 1 < 4) ? a0p[j + 1] : a1p[j - 3];
                    float w1b = (j + 1 < 4) ? b0p[j + 1] : b1p[j - 3];
                    float ua = fmaf(c0v[p], w0a, c1v[p] * w1a);
                    float ub = fmaf(c0v[p], w0b, c1v[p] * w1b);
                    auto pk = __builtin_amdgcn_cvt_pkrtz(ssp_u(ua), ssp_u(ub));
                    ah[p][j] = pk[0];
                    ah[p][j + 1] = pk[1];
                }
            }
            const _Float16* bhp = w2f + (size_t)(kt * 8) * 512 + (size_t)lane * 8;
            #pragma unroll
            for (int nt = 0; nt < 8; ++nt) {
                half8 bh = *reinterpret_cast<const half8*>(bhp + nt * 512);
                acc[0][nt] = __builtin_amdgcn_mfma_f32_16x16x32_f16(ah[0], bh, acc[0][nt], 0, 0, 0);
                acc[1][nt] = __builtin_amdgcn_mfma_f32_16x16x32_f16(ah[1], bh, acc[1][nt], 0, 0, 0);
            }
        }

        // ---- per-b epilogue ----
        #pragma unroll
        for (int p = 0; p < 2; ++p) {
            const int bl = pass * 2 + p;

            // base-2 ssp + per-kt fp16 transpose through wave-private LDS
            f32x4 T0 = {0.f, 0.f, 0.f, 0.f};
            f32x4 T1 = {0.f, 0.f, 0.f, 0.f};
            #pragma unroll
            for (int kt = 0; kt < 4; ++kt) {
                #pragma unroll
                for (int ntl = 0; ntl < 2; ++ntl)
                    #pragma unroll
                    for (int reg = 0; reg < 4; ++reg)
                        sH2t[wv][quad * 4 + reg][ntl * 16 + m] =
                            (_Float16)ssp_u(acc[p][kt * 2 + ntl][reg] * C_EPSC);
                half8 ah2 = *reinterpret_cast<const half8*>(&sH2t[wv][m][quad * 8]);
                half8 bv = *reinterpret_cast<const half8*>(sVf + (bl * 4 + kt) * 512 + lane * 8);
                if (kt & 1) T1 = __builtin_amdgcn_mfma_f32_16x16x32_f16(ah2, bv, T1, 0, 0, 0);
                else        T0 = __builtin_amdgcn_mfma_f32_16x16x32_f16(ah2, bv, T0, 0, 0, 0);
            }

            // G-weight; reduce DEFERRED: accumulate unreduced lane-partials
            const int comp = (m >= 1 && m <= 8) ? (m - 1) : 0;
            #pragma unroll
            for (int reg = 0; reg < 4; ++reg) {
                const int row = quad * 4 + reg;
                const float Tv = T0[reg] + T1[reg];
                const float yv = sYw[wv][p][row][comp];
                const float g = (m == 0) ? 1.0f : ((m <= 8) ? yv : 0.0f);
                outAcc[reg] = fmaf(Tv, g, outAcc[reg]);
            }
        }
    }

    // ---- single 16-lane shuffle reduce ----
    #pragma unroll
    for (int off = 1; off < 16; off <<= 1)
        #pragma unroll
        for (int reg = 0; reg < 4; ++reg)
            outAcc[reg] += __shfl_xor(outAcc[reg], off);

    // ---- write partial[z][bg][a]: lanes m==0 hold a = wv*16 + quad*4 + reg ----
    if (m == 0) {
        float4 st;
        st.x = outAcc[0]; st.y = outAcc[1]; st.z = outAcc[2]; st.w = outAcc[3];
        *reinterpret_cast<float4*>(partial + ((size_t)(z * 8 + bg)) * 64 + wv * 16 + quad * 4) = st;
    }
}

// ---------------------------------------------------------------------------
// finalize: out[z,a] = sp( (sum_bg partial) / sqrt(n_atoms) ) * mask
// ---------------------------------------------------------------------------
__global__ __launch_bounds__(64, 8)
void finalize(const float* __restrict__ partial, const float* __restrict__ mask,
              float* __restrict__ out) {
    const int z = blockIdx.x, a = threadIdx.x;
    const float mk = mask[z * 64 + a];
    float s = mk;
    #pragma unroll
    for (int off = 32; off > 0; off >>= 1) s += __shfl_xor(s, off);
    const float inv = rsqrtf(s);
    float acc = 0.f;
    #pragma unroll
    for (int bg = 0; bg < 8; ++bg)
        acc += partial[((size_t)(z * 8 + bg)) * 64 + a];
    out[z * 64 + a] = sp_f(acc * inv) * mk;
}

extern "C" void kernel_launch(void* const* d_in, const int* in_sizes, int n_in,
                              void* d_out, int out_size, void* d_ws, size_t ws_size,
                              hipStream_t stream) {
    const float* rep  = (const float*)d_in[0];
    const float* geom = (const float*)d_in[1];
    const float* mask = (const float*)d_in[2];
    const float* W1   = (const float*)d_in[3];
    const float* W2   = (const float*)d_in[4];
    const float* W3   = (const float*)d_in[5];
    float* out = (float*)d_out;

    _Float16* w2f = (_Float16*)d_ws;                          // 32768 B
    float* partial = (float*)((char*)d_ws + 32768);           // 512*64*4 = 131072 B

    pair4<<<dim3(8, 64), 256, 0, stream>>>(rep, geom, W1, W2, W3, w2f, partial);
    finalize<<<64, 64, 0, stream>>>(partial, mask, out);
}